// Round 1
// baseline (1469.728 us; speedup 1.0000x reference)
//
#include <hip/hip_runtime.h>
#include <hip/hip_bf16.h>

// ---------------- problem constants ----------------
constexpr int BATCH = 64;
constexpr int H1 = 126, W1 = 126, C1 = 16;   // conv1 out
constexpr int H2 = 124, W2 = 124, C2 = 32;   // conv2 out
constexpr int H3 = 122, W3 = 122, C3 = 40;   // conv3 out (x)
constexpr int HW3 = H3 * W3;                 // 14884

// ws layout (float elements)
constexpr size_t A1_OFF  = 0;
constexpr size_t A1_SZ   = (size_t)BATCH * C1 * H1 * W1;
constexpr size_t A2_OFF  = A1_OFF + A1_SZ;
constexpr size_t A2_SZ   = (size_t)BATCH * C2 * H2 * W2;
constexpr size_t QKW_OFF = A2_OFF + A2_SZ;       // 160 floats
constexpr size_t SMAT_OFF = QKW_OFF + 160;       // 64*4*40 floats

// out layout (float elements)
constexpr size_t X_SZ    = (size_t)BATCH * C3 * HW3;
constexpr size_t PT_OFF  = X_SZ;
constexpr size_t FEAT_OFF = PT_OFF + BATCH * 8;
constexpr size_t ATT_OFF  = FEAT_OFF + BATCH * 40;

// ---------------- tiny: fold query into k_w ----------------
__global__ void k_qkw(const float* __restrict__ query, const float* __restrict__ k_w,
                      float* __restrict__ qkw) {
    int t = threadIdx.x;
    if (t < 160) {
        int q = t / 40, c = t % 40;
        float s = 0.f;
        #pragma unroll
        for (int d = 0; d < 10; ++d)
            s = fmaf(query[q * 10 + d], k_w[(d * 4 + q) * 40 + c], s);
        qkw[t] = s * (1.0f / 122.0f);   // scale = sqrt(122*122)
    }
}

// ---------------- conv1: 5->16, 128->126, coords inline ----------------
__global__ __launch_bounds__(256) void k_conv1(const float* __restrict__ img,
                                               const float* __restrict__ w1,
                                               const float* __restrict__ b1,
                                               float* __restrict__ a1) {
    __shared__ float lin[5][18][10];   // input patch (16+2 rows, 8+2 cols)
    __shared__ float lw[45][16];       // weights transposed [cin*9][oc]
    const int b = blockIdx.z;
    const int r0 = blockIdx.y * 16;
    const int c0 = blockIdx.x * 8;
    const int t = threadIdx.x;

    for (int i = t; i < 720; i += 256) {
        int oc = i / 45, r = i % 45;
        lw[r][oc] = w1[i];
    }
    for (int i = t; i < 900; i += 256) {
        int c = i / 180, rr = (i % 180) / 10, px = i % 10;
        int sr = min(r0 + rr, 127), sc = min(c0 + px, 127);
        float v;
        if (c < 3)       v = img[((size_t)b * 3 + c) * (128 * 128) + sr * 128 + sc];
        else if (c == 3) v = -1.0f + (2.0f / 127.0f) * (float)sr;  // xx along H
        else             v = -1.0f + (2.0f / 127.0f) * (float)sc;  // yy along W
        lin[c][rr][px] = v;
    }
    __syncthreads();

    const int oc = t & 15, sp = t >> 4;   // 16 oc x 16 rows
    float acc[8];
    const float bias = b1[oc];
    #pragma unroll
    for (int j = 0; j < 8; ++j) acc[j] = bias;

    #pragma unroll
    for (int cl = 0; cl < 5; ++cl) {
        float w9[9];
        #pragma unroll
        for (int k = 0; k < 9; ++k) w9[k] = lw[cl * 9 + k][oc];
        #pragma unroll
        for (int ky = 0; ky < 3; ++ky) {
            float in10[10];
            #pragma unroll
            for (int j = 0; j < 10; ++j) in10[j] = lin[cl][sp + ky][j];
            #pragma unroll
            for (int kx = 0; kx < 3; ++kx)
                #pragma unroll
                for (int j = 0; j < 8; ++j)
                    acc[j] = fmaf(in10[kx + j], w9[ky * 3 + kx], acc[j]);
        }
    }
    const int orow = r0 + sp;
    if (orow < H1) {
        float* op = a1 + ((size_t)b * C1 + oc) * (H1 * W1) + orow * W1 + c0;
        #pragma unroll
        for (int j = 0; j < 8; ++j)
            if (c0 + j < W1) op[j] = fmaxf(acc[j], 0.0f);
    }
}

// ---------------- conv2: 16->32, 126->124 ----------------
__global__ __launch_bounds__(256) void k_conv2(const float* __restrict__ a1,
                                               const float* __restrict__ w2,
                                               const float* __restrict__ b2,
                                               float* __restrict__ a2) {
    __shared__ float lin[8][10][10];
    __shared__ float lw[72][32];
    const int b = blockIdx.z;
    const int r0 = blockIdx.y * 8, c0 = blockIdx.x * 8;
    const int t = threadIdx.x;
    const int oc = t & 31, sp = t >> 5;   // 32 oc x 8 rows

    float acc[8];
    const float bias = b2[oc];
    #pragma unroll
    for (int j = 0; j < 8; ++j) acc[j] = bias;

    for (int ck = 0; ck < 16; ck += 8) {
        __syncthreads();
        for (int i = t; i < 800; i += 256) {
            int cl = i / 100, rr = (i % 100) / 10, px = i % 10;
            int sr = min(r0 + rr, H1 - 1), sc = min(c0 + px, W1 - 1);
            lin[cl][rr][px] = a1[((size_t)b * C1 + ck + cl) * (H1 * W1) + sr * W1 + sc];
        }
        for (int i = t; i < 32 * 72; i += 256) {
            int ocs = i / 72, r = i % 72;
            lw[r][ocs] = w2[ocs * 144 + ck * 9 + r];
        }
        __syncthreads();
        #pragma unroll
        for (int cl = 0; cl < 8; ++cl) {
            float w9[9];
            #pragma unroll
            for (int k = 0; k < 9; ++k) w9[k] = lw[cl * 9 + k][oc];
            #pragma unroll
            for (int ky = 0; ky < 3; ++ky) {
                float in10[10];
                #pragma unroll
                for (int j = 0; j < 10; ++j) in10[j] = lin[cl][sp + ky][j];
                #pragma unroll
                for (int kx = 0; kx < 3; ++kx)
                    #pragma unroll
                    for (int j = 0; j < 8; ++j)
                        acc[j] = fmaf(in10[kx + j], w9[ky * 3 + kx], acc[j]);
            }
        }
    }
    const int orow = r0 + sp;
    if (orow < H2) {
        float* op = a2 + ((size_t)b * C2 + oc) * (H2 * W2) + orow * W2 + c0;
        #pragma unroll
        for (int j = 0; j < 8; ++j)
            if (c0 + j < W2) op[j] = fmaxf(acc[j], 0.0f);
    }
}

// ---------------- conv3: 32->40, 124->122, writes x ----------------
__global__ __launch_bounds__(320) void k_conv3(const float* __restrict__ a2,
                                               const float* __restrict__ w3,
                                               const float* __restrict__ b3,
                                               float* __restrict__ x) {
    __shared__ float lin[8][10][10];
    __shared__ float lw[72][40];
    const int b = blockIdx.z;
    const int r0 = blockIdx.y * 8, c0 = blockIdx.x * 8;
    const int t = threadIdx.x;
    const int oc = t % 40, sp = t / 40;   // 40 oc x 8 rows

    float acc[8];
    const float bias = b3[oc];
    #pragma unroll
    for (int j = 0; j < 8; ++j) acc[j] = bias;

    for (int ck = 0; ck < 32; ck += 8) {
        __syncthreads();
        for (int i = t; i < 800; i += 320) {
            int cl = i / 100, rr = (i % 100) / 10, px = i % 10;
            int sr = min(r0 + rr, H2 - 1), sc = min(c0 + px, W2 - 1);
            lin[cl][rr][px] = a2[((size_t)b * C2 + ck + cl) * (H2 * W2) + sr * W2 + sc];
        }
        for (int i = t; i < 40 * 72; i += 320) {
            int ocs = i / 72, r = i % 72;
            lw[r][ocs] = w3[ocs * (32 * 9) + ck * 9 + r];
        }
        __syncthreads();
        #pragma unroll
        for (int cl = 0; cl < 8; ++cl) {
            float w9[9];
            #pragma unroll
            for (int k = 0; k < 9; ++k) w9[k] = lw[cl * 9 + k][oc];
            #pragma unroll
            for (int ky = 0; ky < 3; ++ky) {
                float in10[10];
                #pragma unroll
                for (int j = 0; j < 10; ++j) in10[j] = lin[cl][sp + ky][j];
                #pragma unroll
                for (int kx = 0; kx < 3; ++kx)
                    #pragma unroll
                    for (int j = 0; j < 8; ++j)
                        acc[j] = fmaf(in10[kx + j], w9[ky * 3 + kx], acc[j]);
            }
        }
    }
    const int orow = r0 + sp;
    if (orow < H3) {
        float* op = x + ((size_t)b * C3 + oc) * HW3 + orow * W3 + c0;
        #pragma unroll
        for (int j = 0; j < 8; ++j)
            if (c0 + j < W3) op[j] = fmaxf(acc[j], 0.0f);
    }
}

// ---------------- scores = qkw . x (written into att region) ----------------
__global__ __launch_bounds__(256) void k_scores(const float* __restrict__ x,
                                                const float* __restrict__ qkw,
                                                float* __restrict__ att) {
    __shared__ float lq[160];
    const int b = blockIdx.y;
    const int p = blockIdx.x * 256 + threadIdx.x;
    for (int i = threadIdx.x; i < 160; i += 256) lq[i] = qkw[i];
    __syncthreads();
    if (p >= HW3) return;
    const float* xp = x + (size_t)b * C3 * HW3 + p;
    float s0 = 0, s1 = 0, s2 = 0, s3 = 0;
    #pragma unroll
    for (int c = 0; c < 40; ++c) {
        float v = xp[(size_t)c * HW3];
        s0 = fmaf(v, lq[c], s0);
        s1 = fmaf(v, lq[40 + c], s1);
        s2 = fmaf(v, lq[80 + c], s2);
        s3 = fmaf(v, lq[120 + c], s3);
    }
    float* ap = att + (size_t)b * 4 * HW3 + p;
    ap[0] = s0; ap[HW3] = s1; ap[2 * HW3] = s2; ap[3 * HW3] = s3;
}

// ---------------- block reduction helpers (256 threads = 4 waves) ----------------
__device__ __forceinline__ float block_max(float v, float* sred) {
    #pragma unroll
    for (int off = 32; off >= 1; off >>= 1) v = fmaxf(v, __shfl_xor(v, off));
    if ((threadIdx.x & 63) == 0) sred[threadIdx.x >> 6] = v;
    __syncthreads();
    float r = fmaxf(fmaxf(sred[0], sred[1]), fmaxf(sred[2], sred[3]));
    __syncthreads();
    return r;
}
__device__ __forceinline__ float block_sum(float v, float* sred) {
    #pragma unroll
    for (int off = 32; off >= 1; off >>= 1) v += __shfl_xor(v, off);
    if ((threadIdx.x & 63) == 0) sred[threadIdx.x >> 6] = v;
    __syncthreads();
    float r = sred[0] + sred[1] + sred[2] + sred[3];
    __syncthreads();
    return r;
}

// ---------------- softmax over HW per (b,q), in place; fuses pt_out ----------------
__global__ __launch_bounds__(256) void k_softmax(float* __restrict__ att,
                                                 float* __restrict__ pt_out) {
    __shared__ float sred[4];
    const int bq = blockIdx.x;      // b*4 + q
    float* row = att + (size_t)bq * HW3;
    const int t = threadIdx.x;

    float m = -1e30f;
    for (int p = t; p < HW3; p += 256) m = fmaxf(m, row[p]);
    m = block_max(m, sred);

    float s = 0.f;
    for (int p = t; p < HW3; p += 256) s += __expf(row[p] - m);
    s = block_sum(s, sred);
    const float inv = 1.0f / s;

    float sx = 0.f, sy = 0.f;
    for (int p = t; p < HW3; p += 256) {
        float w = __expf(row[p] - m) * inv;
        row[p] = w;
        int pr = p / W3, pc = p % W3;
        sx = fmaf(w, (float)pc * (1.0f / (W3 - 1)), sx);
        sy = fmaf(w, (float)pr * (1.0f / (H3 - 1)), sy);
    }
    sx = block_sum(sx, sred);
    sy = block_sum(sy, sred);
    if (t == 0) { pt_out[bq * 2] = sx; pt_out[bq * 2 + 1] = sy; }
}

// ---------------- s[b][q][c] = sum_p att[b,q,p] * x[b,c,p] ----------------
__global__ __launch_bounds__(256) void k_smat(const float* __restrict__ x,
                                              const float* __restrict__ att,
                                              float* __restrict__ smat) {
    __shared__ float sred[4];
    const int c = blockIdx.x, b = blockIdx.y;
    const float* xp = x + ((size_t)b * C3 + c) * HW3;
    const float* ap = att + (size_t)b * 4 * HW3;
    float a0 = 0, a1 = 0, a2 = 0, a3 = 0;
    for (int p = threadIdx.x; p < HW3; p += 256) {
        float v = xp[p];
        a0 = fmaf(v, ap[p], a0);
        a1 = fmaf(v, ap[HW3 + p], a1);
        a2 = fmaf(v, ap[2 * HW3 + p], a2);
        a3 = fmaf(v, ap[3 * HW3 + p], a3);
    }
    a0 = block_sum(a0, sred);
    a1 = block_sum(a1, sred);
    a2 = block_sum(a2, sred);
    a3 = block_sum(a3, sred);
    if (threadIdx.x == 0) {
        smat[((size_t)b * 4 + 0) * 40 + c] = a0;
        smat[((size_t)b * 4 + 1) * 40 + c] = a1;
        smat[((size_t)b * 4 + 2) * 40 + c] = a2;
        smat[((size_t)b * 4 + 3) * 40 + c] = a3;
    }
}

// ---------------- feat_out[b][q*10+d] = sum_c f_w[d*4+q][c] * s[b][q][c] ----------------
__global__ void k_feat(const float* __restrict__ smat, const float* __restrict__ f_w,
                       float* __restrict__ feat) {
    const int b = blockIdx.x, t = threadIdx.x;
    if (t < 40) {
        int q = t / 10, d = t % 10;
        float s = 0.f;
        #pragma unroll
        for (int c = 0; c < 40; ++c)
            s = fmaf(f_w[(d * 4 + q) * 40 + c], smat[((size_t)b * 4 + q) * 40 + c], s);
        feat[b * 40 + t] = s;
    }
}

// ---------------- launch ----------------
extern "C" void kernel_launch(void* const* d_in, const int* in_sizes, int n_in,
                              void* d_out, int out_size, void* d_ws, size_t ws_size,
                              hipStream_t stream) {
    const float* img   = (const float*)d_in[0];
    const float* w1    = (const float*)d_in[1];
    const float* b1    = (const float*)d_in[2];
    const float* w2    = (const float*)d_in[3];
    const float* b2    = (const float*)d_in[4];
    const float* w3    = (const float*)d_in[5];
    const float* b3    = (const float*)d_in[6];
    const float* k_w   = (const float*)d_in[7];
    const float* f_w   = (const float*)d_in[8];
    const float* query = (const float*)d_in[9];

    float* out  = (float*)d_out;
    float* ws   = (float*)d_ws;
    float* a1   = ws + A1_OFF;
    float* a2   = ws + A2_OFF;
    float* qkw  = ws + QKW_OFF;
    float* smat = ws + SMAT_OFF;

    float* x    = out;
    float* pt   = out + PT_OFF;
    float* feat = out + FEAT_OFF;
    float* att  = out + ATT_OFF;

    k_qkw<<<1, 256, 0, stream>>>(query, k_w, qkw);
    k_conv1<<<dim3(16, 8, BATCH), 256, 0, stream>>>(img, w1, b1, a1);
    k_conv2<<<dim3(16, 16, BATCH), 256, 0, stream>>>(a1, w2, b2, a2);
    k_conv3<<<dim3(16, 16, BATCH), 320, 0, stream>>>(a2, w3, b3, x);
    k_scores<<<dim3((HW3 + 255) / 256, BATCH), 256, 0, stream>>>(x, qkw, att);
    k_softmax<<<BATCH * 4, 256, 0, stream>>>(att, pt);
    k_smat<<<dim3(40, BATCH), 256, 0, stream>>>(x, att, smat);
    k_feat<<<BATCH, 64, 0, stream>>>(smat, f_w, feat);
}

// Round 2
// 499.410 us; speedup vs baseline: 2.9429x; 2.9429x over previous
//
#include <hip/hip_runtime.h>
#include <hip/hip_bf16.h>

// ---------------- problem constants ----------------
constexpr int BATCH = 64;
constexpr int H1 = 126, W1 = 126, C1 = 16;   // conv1 out
constexpr int H2 = 124, W2 = 124, C2 = 32;   // conv2 out
constexpr int H3 = 122, W3 = 122, C3 = 40;   // conv3 out (x)
constexpr int HW3 = H3 * W3;                 // 14884

typedef __attribute__((ext_vector_type(8))) short bf16x8;
typedef __attribute__((ext_vector_type(4))) float f32x4;

__device__ __forceinline__ ushort f2bf(float f) {
    __hip_bfloat16 h = __float2bfloat16(f);
    return *reinterpret_cast<ushort*>(&h);
}

// ---------------- ws layout (bytes) ----------------
constexpr size_t A1_B   = 0;                                   // bf16 NHWC (64,126,126,16)
constexpr size_t A1_SZB = (size_t)BATCH * H1 * W1 * C1 * 2;
constexpr size_t A2_B   = (A1_B + A1_SZB + 255) & ~(size_t)255; // bf16 NHWC (64,124,124,32)
constexpr size_t A2_SZB = (size_t)BATCH * H2 * W2 * C2 * 2;
constexpr size_t BT2_B  = (A2_B + A2_SZB + 255) & ~(size_t)255; // bf16 [32][160]
constexpr size_t BT3_B  = (BT2_B + 32 * 160 * 2 + 255) & ~(size_t)255; // bf16 [48][288]
constexpr size_t QKW_B  = (BT3_B + 48 * 288 * 2 + 255) & ~(size_t)255; // f32 [160]
constexpr size_t SMAT_B = (QKW_B + 160 * 4 + 255) & ~(size_t)255;      // f32 [64][4][40]

// out layout (float elements)
constexpr size_t X_SZ     = (size_t)BATCH * C3 * HW3;
constexpr size_t PT_OFF   = X_SZ;
constexpr size_t FEAT_OFF = PT_OFF + BATCH * 8;
constexpr size_t ATT_OFF  = FEAT_OFF + BATCH * 40;

// ---------------- fold query into k_w; scale 1/122 ----------------
__global__ void k_qkw(const float* __restrict__ query, const float* __restrict__ k_w,
                      float* __restrict__ qkw) {
    int t = threadIdx.x;
    if (t < 160) {
        int q = t / 40, c = t % 40;
        float s = 0.f;
        #pragma unroll
        for (int d = 0; d < 10; ++d)
            s = fmaf(query[q * 10 + d], k_w[(d * 4 + q) * 40 + c], s);
        qkw[t] = s * (1.0f / 122.0f);
    }
}

// ---------------- weight transform: Bt[n][k] bf16, zero-padded ----------------
__global__ void k_bt(const float* __restrict__ w2, ushort* __restrict__ bt2,
                     const float* __restrict__ w3, ushort* __restrict__ bt3) {
    int t = blockIdx.x * 256 + threadIdx.x;
    if (t < 32 * 160) {                       // bt2: K=144 pad 160
        int n = t / 160, k = t % 160;
        float v = 0.f;
        if (k < 144) { int c = k & 15, cell = k >> 4; v = w2[(n * 16 + c) * 9 + cell]; }
        bt2[t] = f2bf(v);
    } else {
        int u = t - 32 * 160;
        if (u < 48 * 288) {                   // bt3: N pad 40->48
            int n = u / 288, k = u % 288;
            float v = 0.f;
            if (n < 40) { int c = k & 31, cell = k >> 5; v = w3[(n * 32 + c) * 9 + cell]; }
            bt3[u] = f2bf(v);
        }
    }
}

// ---------------- conv1: 5->16, coords inline, fp32 direct, NHWC bf16 out ----------------
__global__ __launch_bounds__(256) void k_conv1(const float* __restrict__ img,
                                               const float* __restrict__ w1,
                                               const float* __restrict__ b1,
                                               ushort* __restrict__ a1) {
    __shared__ float lin[5][18][10];
    __shared__ float lw[45][16];
    const int b = blockIdx.z;
    const int r0 = blockIdx.y * 16;
    const int c0 = blockIdx.x * 8;
    const int t = threadIdx.x;

    for (int i = t; i < 720; i += 256) {
        int oc = i / 45, r = i % 45;
        lw[r][oc] = w1[i];
    }
    for (int i = t; i < 900; i += 256) {
        int c = i / 180, rr = (i % 180) / 10, px = i % 10;
        int sr = min(r0 + rr, 127), sc = min(c0 + px, 127);
        float v;
        if (c < 3)       v = img[((size_t)b * 3 + c) * (128 * 128) + sr * 128 + sc];
        else if (c == 3) v = -1.0f + (2.0f / 127.0f) * (float)sr;
        else             v = -1.0f + (2.0f / 127.0f) * (float)sc;
        lin[c][rr][px] = v;
    }
    __syncthreads();

    const int oc = t & 15, sp = t >> 4;
    float acc[8];
    const float bias = b1[oc];
    #pragma unroll
    for (int j = 0; j < 8; ++j) acc[j] = bias;

    #pragma unroll
    for (int cl = 0; cl < 5; ++cl) {
        float w9[9];
        #pragma unroll
        for (int k = 0; k < 9; ++k) w9[k] = lw[cl * 9 + k][oc];
        #pragma unroll
        for (int ky = 0; ky < 3; ++ky) {
            float in10[10];
            #pragma unroll
            for (int j = 0; j < 10; ++j) in10[j] = lin[cl][sp + ky][j];
            #pragma unroll
            for (int kx = 0; kx < 3; ++kx)
                #pragma unroll
                for (int j = 0; j < 8; ++j)
                    acc[j] = fmaf(in10[kx + j], w9[ky * 3 + kx], acc[j]);
        }
    }
    const int orow = r0 + sp;
    if (orow < H1) {
        ushort* op = a1 + (((size_t)b * H1 + orow) * W1 + c0) * C1 + oc;
        #pragma unroll
        for (int j = 0; j < 8; ++j)
            if (c0 + j < W1) op[(size_t)j * C1] = f2bf(fmaxf(acc[j], 0.0f));
    }
}

// ---------------- conv2: implicit GEMM MFMA, NHWC bf16 in/out ----------------
// M=124(pad128) spatial, N=32, K=144(pad160). Block per (b,y), 4 waves.
__global__ __launch_bounds__(256) void k_conv2_mfma(const ushort* __restrict__ a1,
                                                    const ushort* __restrict__ bt2,
                                                    const float* __restrict__ b2,
                                                    ushort* __restrict__ a2) {
    const int b = blockIdx.y, y = blockIdx.x;
    const int t = threadIdx.x, lane = t & 63, w = t >> 6;
    const int col = lane & 15, g = lane >> 4;

    f32x4 acc[2][2];
    #pragma unroll
    for (int mi = 0; mi < 2; ++mi)
        #pragma unroll
        for (int nf = 0; nf < 2; ++nf) {
            float bv = b2[nf * 16 + col];
            acc[mi][nf] = (f32x4){bv, bv, bv, bv};
        }

    #pragma unroll
    for (int ks = 0; ks < 5; ++ks) {
        bf16x8 bf[2];
        #pragma unroll
        for (int nf = 0; nf < 2; ++nf)
            bf[nf] = *(const bf16x8*)(bt2 + (size_t)(nf * 16 + col) * 160 + ks * 32 + 8 * g);

        const int cell = 2 * ks + (g >> 1);       // (ky*3+kx), <=8 valid
        const bool valid = (cell <= 8);
        const int ky = cell / 3, kx = cell - ky * 3;
        const int c0 = 8 * (g & 1);

        #pragma unroll
        for (int mi = 0; mi < 2; ++mi) {
            const int xp = (w * 2 + mi) * 16 + col;
            bf16x8 af = (bf16x8)0;
            if (valid) {
                const int xin = min(xp + kx, W1 - 1);
                af = *(const bf16x8*)(a1 + (((size_t)b * H1 + (y + ky)) * W1 + xin) * C1 + c0);
            }
            #pragma unroll
            for (int nf = 0; nf < 2; ++nf)
                acc[mi][nf] = __builtin_amdgcn_mfma_f32_16x16x32_bf16(af, bf[nf], acc[mi][nf], 0, 0, 0);
        }
    }

    #pragma unroll
    for (int mi = 0; mi < 2; ++mi) {
        const int xp0 = (w * 2 + mi) * 16 + 4 * g;
        #pragma unroll
        for (int r = 0; r < 4; ++r) {
            const int xp = xp0 + r;
            if (xp < W2) {
                ushort* op = a2 + (((size_t)b * H2 + y) * W2 + xp) * C2;
                #pragma unroll
                for (int nf = 0; nf < 2; ++nf)
                    op[nf * 16 + col] = f2bf(fmaxf(acc[mi][nf][r], 0.0f));
            }
        }
    }
}

// ---------------- conv3: implicit GEMM MFMA + fused scores ----------------
// M=122(pad128), N=40(pad48), K=288. Block per (b,y). Writes x (NCHW f32) + att logits.
__global__ __launch_bounds__(256) void k_conv3_mfma(const ushort* __restrict__ a2,
                                                    const ushort* __restrict__ bt3,
                                                    const float* __restrict__ b3,
                                                    const float* __restrict__ qkw,
                                                    float* __restrict__ x,
                                                    float* __restrict__ att) {
    __shared__ float sx[128][41];
    __shared__ float lq[160];
    const int b = blockIdx.y, y = blockIdx.x;
    const int t = threadIdx.x, lane = t & 63, w = t >> 6;
    const int col = lane & 15, g = lane >> 4;

    f32x4 acc[2][3];
    #pragma unroll
    for (int mi = 0; mi < 2; ++mi)
        #pragma unroll
        for (int nf = 0; nf < 3; ++nf) {
            const int ch = nf * 16 + col;
            float bv = (ch < 40) ? b3[ch] : 0.f;
            acc[mi][nf] = (f32x4){bv, bv, bv, bv};
        }

    #pragma unroll
    for (int ky = 0; ky < 3; ++ky) {
        const ushort* arow = a2 + ((size_t)b * H2 + (y + ky)) * W2 * C2;
        #pragma unroll
        for (int kx = 0; kx < 3; ++kx) {
            const int ks = ky * 3 + kx;
            bf16x8 bf[3];
            #pragma unroll
            for (int nf = 0; nf < 3; ++nf)
                bf[nf] = *(const bf16x8*)(bt3 + (size_t)(nf * 16 + col) * 288 + ks * 32 + 8 * g);
            #pragma unroll
            for (int mi = 0; mi < 2; ++mi) {
                const int xp = (w * 2 + mi) * 16 + col;
                const int xin = min(xp + kx, W2 - 1);
                bf16x8 af = *(const bf16x8*)(arow + (size_t)xin * C2 + 8 * g);
                #pragma unroll
                for (int nf = 0; nf < 3; ++nf)
                    acc[mi][nf] = __builtin_amdgcn_mfma_f32_16x16x32_bf16(af, bf[nf], acc[mi][nf], 0, 0, 0);
            }
        }
    }

    // stage to LDS (ReLU applied), load qkw
    for (int i = t; i < 160; i += 256) lq[i] = qkw[i];
    #pragma unroll
    for (int mi = 0; mi < 2; ++mi) {
        const int xp0 = (w * 2 + mi) * 16 + 4 * g;
        #pragma unroll
        for (int nf = 0; nf < 3; ++nf) {
            const int ch = nf * 16 + col;
            if (ch < 40) {
                #pragma unroll
                for (int r = 0; r < 4; ++r)
                    sx[xp0 + r][ch] = fmaxf(acc[mi][nf][r], 0.0f);
            }
        }
    }
    __syncthreads();

    if (t < W3) {
        float v[40];
        #pragma unroll
        for (int c = 0; c < 40; ++c) v[c] = sx[t][c];
        const size_t pbase = (size_t)b * C3 * HW3 + (size_t)y * W3 + t;
        #pragma unroll
        for (int c = 0; c < 40; ++c) x[pbase + (size_t)c * HW3] = v[c];
        float s0 = 0, s1 = 0, s2 = 0, s3 = 0;
        #pragma unroll
        for (int c = 0; c < 40; ++c) {
            s0 = fmaf(v[c], lq[c], s0);
            s1 = fmaf(v[c], lq[40 + c], s1);
            s2 = fmaf(v[c], lq[80 + c], s2);
            s3 = fmaf(v[c], lq[120 + c], s3);
        }
        const size_t abase = (size_t)b * 4 * HW3 + (size_t)y * W3 + t;
        att[abase] = s0;
        att[abase + HW3] = s1;
        att[abase + 2 * HW3] = s2;
        att[abase + 3 * HW3] = s3;
    }
}

// ---------------- block reduction helpers ----------------
__device__ __forceinline__ float block_max(float v, float* sred) {
    #pragma unroll
    for (int off = 32; off >= 1; off >>= 1) v = fmaxf(v, __shfl_xor(v, off));
    if ((threadIdx.x & 63) == 0) sred[threadIdx.x >> 6] = v;
    __syncthreads();
    float r = fmaxf(fmaxf(sred[0], sred[1]), fmaxf(sred[2], sred[3]));
    __syncthreads();
    return r;
}
__device__ __forceinline__ float block_sum(float v, float* sred) {
    #pragma unroll
    for (int off = 32; off >= 1; off >>= 1) v += __shfl_xor(v, off);
    if ((threadIdx.x & 63) == 0) sred[threadIdx.x >> 6] = v;
    __syncthreads();
    float r = sred[0] + sred[1] + sred[2] + sred[3];
    __syncthreads();
    return r;
}

// ---------------- softmax over HW per (b,q), in place; fuses pt_out ----------------
__global__ __launch_bounds__(256) void k_softmax(float* __restrict__ att,
                                                 float* __restrict__ pt_out) {
    __shared__ float sred[4];
    const int bq = blockIdx.x;
    float* row = att + (size_t)bq * HW3;
    const int t = threadIdx.x;

    float m = -1e30f;
    for (int p = t; p < HW3; p += 256) m = fmaxf(m, row[p]);
    m = block_max(m, sred);

    float s = 0.f;
    for (int p = t; p < HW3; p += 256) s += __expf(row[p] - m);
    s = block_sum(s, sred);
    const float inv = 1.0f / s;

    float sx = 0.f, sy = 0.f;
    for (int p = t; p < HW3; p += 256) {
        float wgt = __expf(row[p] - m) * inv;
        row[p] = wgt;
        int pr = p / W3, pc = p % W3;
        sx = fmaf(wgt, (float)pc * (1.0f / (W3 - 1)), sx);
        sy = fmaf(wgt, (float)pr * (1.0f / (H3 - 1)), sy);
    }
    sx = block_sum(sx, sred);
    sy = block_sum(sy, sred);
    if (t == 0) { pt_out[bq * 2] = sx; pt_out[bq * 2 + 1] = sy; }
}

// ---------------- s[b][q][c] = sum_p att[b,q,p] * x[b,c,p] ----------------
__global__ __launch_bounds__(256) void k_smat(const float* __restrict__ x,
                                              const float* __restrict__ att,
                                              float* __restrict__ smat) {
    __shared__ float sred[4];
    const int c = blockIdx.x, b = blockIdx.y;
    const float* xp = x + ((size_t)b * C3 + c) * HW3;
    const float* ap = att + (size_t)b * 4 * HW3;
    float a0 = 0, a1 = 0, a2 = 0, a3 = 0;
    for (int p = threadIdx.x; p < HW3; p += 256) {
        float v = xp[p];
        a0 = fmaf(v, ap[p], a0);
        a1 = fmaf(v, ap[HW3 + p], a1);
        a2 = fmaf(v, ap[2 * HW3 + p], a2);
        a3 = fmaf(v, ap[3 * HW3 + p], a3);
    }
    a0 = block_sum(a0, sred);
    a1 = block_sum(a1, sred);
    a2 = block_sum(a2, sred);
    a3 = block_sum(a3, sred);
    if (threadIdx.x == 0) {
        smat[((size_t)b * 4 + 0) * 40 + c] = a0;
        smat[((size_t)b * 4 + 1) * 40 + c] = a1;
        smat[((size_t)b * 4 + 2) * 40 + c] = a2;
        smat[((size_t)b * 4 + 3) * 40 + c] = a3;
    }
}

// ---------------- feat_out ----------------
__global__ void k_feat(const float* __restrict__ smat, const float* __restrict__ f_w,
                       float* __restrict__ feat) {
    const int b = blockIdx.x, t = threadIdx.x;
    if (t < 40) {
        int q = t / 10, d = t % 10;
        float s = 0.f;
        #pragma unroll
        for (int c = 0; c < 40; ++c)
            s = fmaf(f_w[(d * 4 + q) * 40 + c], smat[((size_t)b * 4 + q) * 40 + c], s);
        feat[b * 40 + t] = s;
    }
}

// ---------------- launch ----------------
extern "C" void kernel_launch(void* const* d_in, const int* in_sizes, int n_in,
                              void* d_out, int out_size, void* d_ws, size_t ws_size,
                              hipStream_t stream) {
    const float* img   = (const float*)d_in[0];
    const float* w1    = (const float*)d_in[1];
    const float* b1    = (const float*)d_in[2];
    const float* w2    = (const float*)d_in[3];
    const float* b2    = (const float*)d_in[4];
    const float* w3    = (const float*)d_in[5];
    const float* b3    = (const float*)d_in[6];
    const float* k_w   = (const float*)d_in[7];
    const float* f_w   = (const float*)d_in[8];
    const float* query = (const float*)d_in[9];

    char* ws = (char*)d_ws;
    ushort* a1  = (ushort*)(ws + A1_B);
    ushort* a2  = (ushort*)(ws + A2_B);
    ushort* bt2 = (ushort*)(ws + BT2_B);
    ushort* bt3 = (ushort*)(ws + BT3_B);
    float*  qkw = (float*)(ws + QKW_B);
    float*  smat= (float*)(ws + SMAT_B);

    float* out  = (float*)d_out;
    float* x    = out;
    float* pt   = out + PT_OFF;
    float* feat = out + FEAT_OFF;
    float* att  = out + ATT_OFF;

    k_qkw<<<1, 256, 0, stream>>>(query, k_w, qkw);
    k_bt<<<(32 * 160 + 48 * 288 + 255) / 256, 256, 0, stream>>>(w2, bt2, w3, bt3);
    k_conv1<<<dim3(16, 8, BATCH), 256, 0, stream>>>(img, w1, b1, a1);
    k_conv2_mfma<<<dim3(H2, BATCH), 256, 0, stream>>>(a1, bt2, b2, a2);
    k_conv3_mfma<<<dim3(H3, BATCH), 256, 0, stream>>>(a2, bt3, b3, qkw, x, att);
    k_softmax<<<BATCH * 4, 256, 0, stream>>>(att, pt);
    k_smat<<<dim3(40, BATCH), 256, 0, stream>>>(x, att, smat);
    k_feat<<<BATCH, 64, 0, stream>>>(smat, f_w, feat);
}

// Round 4
// 416.081 us; speedup vs baseline: 3.5323x; 1.2003x over previous
//
#include <hip/hip_runtime.h>
#include <hip/hip_bf16.h>

// ---------------- problem constants ----------------
constexpr int BATCH = 64;
constexpr int H1 = 126, W1 = 126, C1 = 16;   // conv1 out
constexpr int H2 = 124, W2 = 124, C2 = 32;   // conv2 out
constexpr int H3 = 122, W3 = 122, C3 = 40;   // conv3 out (x)
constexpr int HW3 = H3 * W3;                 // 14884

typedef __attribute__((ext_vector_type(8))) short bf16x8;
typedef __attribute__((ext_vector_type(4))) float f32x4;

__device__ __forceinline__ ushort f2bf(float f) {
    __hip_bfloat16 h = __float2bfloat16(f);
    return *reinterpret_cast<ushort*>(&h);
}

// ---------------- ws layout (bytes) ----------------
constexpr size_t IMGN_B  = 0;                                    // bf16 NHWC8 (64,128,128,8)
constexpr size_t IMGN_SZ = (size_t)BATCH * 128 * 128 * 8 * 2;
constexpr size_t A1_B    = (IMGN_B + IMGN_SZ + 255) & ~(size_t)255;   // bf16 NHWC (64,126,126,16)
constexpr size_t A1_SZB  = (size_t)BATCH * H1 * W1 * C1 * 2;
constexpr size_t A2_B    = (A1_B + A1_SZB + 255) & ~(size_t)255;      // bf16 NHWC (64,124,124,32)
constexpr size_t A2_SZB  = (size_t)BATCH * H2 * W2 * C2 * 2;
constexpr size_t BT1_B   = (A2_B + A2_SZB + 255) & ~(size_t)255;      // bf16 [16][96]
constexpr size_t BT2_B   = (BT1_B + 16 * 96 * 2 + 255) & ~(size_t)255;   // bf16 [32][160]
constexpr size_t BT3_B   = (BT2_B + 32 * 160 * 2 + 255) & ~(size_t)255;  // bf16 [48][288]
constexpr size_t QKW_B   = (BT3_B + 48 * 288 * 2 + 255) & ~(size_t)255;  // f32 [160]
constexpr size_t SMAT_B  = (QKW_B + 160 * 4 + 255) & ~(size_t)255;       // f32 [64][4][40]

// out layout (float elements)
constexpr size_t X_SZ     = (size_t)BATCH * C3 * HW3;
constexpr size_t PT_OFF   = X_SZ;
constexpr size_t FEAT_OFF = PT_OFF + BATCH * 8;
constexpr size_t ATT_OFF  = FEAT_OFF + BATCH * 40;

// ---------------- fold query into k_w; scale 1/122 ----------------
__global__ void k_qkw(const float* __restrict__ query, const float* __restrict__ k_w,
                      float* __restrict__ qkw) {
    int t = threadIdx.x;
    if (t < 160) {
        int q = t / 40, c = t % 40;
        float s = 0.f;
        #pragma unroll
        for (int d = 0; d < 10; ++d)
            s = fmaf(query[q * 10 + d], k_w[(d * 4 + q) * 40 + c], s);
        qkw[t] = s * (1.0f / 122.0f);
    }
}

// ---------------- weight transforms: Bt[n][k] bf16, zero-padded ----------------
__global__ void k_bt(const float* __restrict__ w1, ushort* __restrict__ bt1,
                     const float* __restrict__ w2, ushort* __restrict__ bt2,
                     const float* __restrict__ w3, ushort* __restrict__ bt3) {
    int t = blockIdx.x * 256 + threadIdx.x;
    if (t < 16 * 96) {                        // bt1: k = cell*8 + c (8-ch slots)
        int oc = t / 96, k = t % 96, cell = k >> 3, c = k & 7;
        float v = (c < 5 && cell < 9) ? w1[(oc * 5 + c) * 9 + cell] : 0.f;
        bt1[t] = f2bf(v);
    } else if (t < 16 * 96 + 32 * 160) {      // bt2: k = cell*16 + c, K=144 pad 160
        int u = t - 16 * 96;
        int n = u / 160, k = u % 160;
        float v = 0.f;
        if (k < 144) { int c = k & 15, cell = k >> 4; v = w2[(n * 16 + c) * 9 + cell]; }
        bt2[u] = f2bf(v);
    } else {
        int u = t - 16 * 96 - 32 * 160;       // bt3: k = cell*32 + c, N pad 40->48
        if (u < 48 * 288) {
            int n = u / 288, k = u % 288;
            float v = 0.f;
            if (n < 40) { int c = k & 31, cell = k >> 5; v = w3[(n * 32 + c) * 9 + cell]; }
            bt3[u] = f2bf(v);
        }
    }
}

// ---------------- pack img + coords into NHWC8 bf16 ----------------
__global__ __launch_bounds__(256) void k_imgN(const float* __restrict__ img,
                                              ushort* __restrict__ imgN) {
    int tid = blockIdx.x * 256 + threadIdx.x;     // 64*128*128 threads
    int b = tid >> 14, pix = tid & 16383;
    int y = pix >> 7, xc = pix & 127;
    const float* ip = img + (size_t)b * 3 * 16384 + pix;
    bf16x8 v;
    v[0] = (short)f2bf(ip[0]);
    v[1] = (short)f2bf(ip[16384]);
    v[2] = (short)f2bf(ip[32768]);
    v[3] = (short)f2bf(-1.0f + (2.0f / 127.0f) * (float)y);   // xx along H
    v[4] = (short)f2bf(-1.0f + (2.0f / 127.0f) * (float)xc);  // yy along W
    v[5] = 0; v[6] = 0; v[7] = 0;
    *(bf16x8*)(imgN + (size_t)tid * 8) = v;
}

// ---------------- conv1: implicit GEMM MFMA, 2 rows/block ----------------
// M=256 (2 rows x 128), N=16, K=96 (12 cell-slots, 9 valid)
__global__ __launch_bounds__(256) void k_conv1_mfma(const ushort* __restrict__ imgN,
                                                    const ushort* __restrict__ bt1,
                                                    const float* __restrict__ b1,
                                                    ushort* __restrict__ a1) {
    __shared__ ushort sx1[256][16];
    const int b = blockIdx.y, y0 = blockIdx.x * 2;
    const int t = threadIdx.x, lane = t & 63, w = t >> 6;
    const int col = lane & 15, g = lane >> 4;
    const int ro = w >> 1, xbase = (w & 1) * 64;

    f32x4 acc[4];
    const float bv = b1[col];
    #pragma unroll
    for (int mi = 0; mi < 4; ++mi) acc[mi] = (f32x4){bv, bv, bv, bv};

    #pragma unroll
    for (int ks = 0; ks < 3; ++ks) {
        bf16x8 bf = *(const bf16x8*)(bt1 + (size_t)col * 96 + ks * 32 + 8 * g);
        const int cell = ks * 4 + g;
        const bool valid = (cell < 9);
        const int ky = cell / 3, kx = cell % 3;
        #pragma unroll
        for (int mi = 0; mi < 4; ++mi) {
            const int xcol = xbase + mi * 16 + col;
            bf16x8 af = (bf16x8)0;
            if (valid) {
                const int row = y0 + ro + ky;
                const int xin = min(xcol + kx, 127);
                af = *(const bf16x8*)(imgN + (((size_t)b * 128 + row) * 128 + xin) * 8);
            }
            acc[mi] = __builtin_amdgcn_mfma_f32_16x16x32_bf16(af, bf, acc[mi], 0, 0, 0);
        }
    }

    #pragma unroll
    for (int mi = 0; mi < 4; ++mi) {
        const int m0 = w * 64 + mi * 16 + 4 * g;
        #pragma unroll
        for (int r = 0; r < 4; ++r)
            sx1[m0 + r][col] = f2bf(fmaxf(acc[mi][r], 0.0f));
    }
    __syncthreads();

    // write rows y0, y0+1: 2 x 126 x 16 ch = 504 ushort8 chunks
    ushort* op = a1 + ((size_t)b * H1 + y0) * W1 * C1;
    for (int i = t; i < 504; i += 256) {
        int ro2 = i / 252, r = i % 252, xcol = r >> 1, c0 = (r & 1) * 8;
        *(bf16x8*)(op + ((size_t)ro2 * W1 + xcol) * C1 + c0) =
            *(const bf16x8*)(&sx1[ro2 * 128 + xcol][c0]);
    }
}

// ---------------- conv2: implicit GEMM MFMA, 2 rows/block ----------------
// M=256, N=32, K=144 pad 160
__global__ __launch_bounds__(256) void k_conv2_mfma(const ushort* __restrict__ a1,
                                                    const ushort* __restrict__ bt2,
                                                    const float* __restrict__ b2,
                                                    ushort* __restrict__ a2) {
    __shared__ ushort sx2[256][40];   // stride 40 keeps 16B chunks aligned
    const int b = blockIdx.y, y0 = blockIdx.x * 2;
    const int t = threadIdx.x, lane = t & 63, w = t >> 6;
    const int col = lane & 15, g = lane >> 4;
    const int ro = w >> 1, xbase = (w & 1) * 64;

    f32x4 acc[4][2];
    #pragma unroll
    for (int mi = 0; mi < 4; ++mi)
        #pragma unroll
        for (int nf = 0; nf < 2; ++nf) {
            float bv = b2[nf * 16 + col];
            acc[mi][nf] = (f32x4){bv, bv, bv, bv};
        }

    #pragma unroll
    for (int ks = 0; ks < 5; ++ks) {
        bf16x8 bf[2];
        #pragma unroll
        for (int nf = 0; nf < 2; ++nf)
            bf[nf] = *(const bf16x8*)(bt2 + (size_t)(nf * 16 + col) * 160 + ks * 32 + 8 * g);
        const int cell = 2 * ks + (g >> 1);
        const bool valid = (cell <= 8);
        const int ky = cell / 3, kx = cell - ky * 3;
        const int c0 = 8 * (g & 1);
        #pragma unroll
        for (int mi = 0; mi < 4; ++mi) {
            const int xcol = xbase + mi * 16 + col;
            bf16x8 af = (bf16x8)0;
            if (valid) {
                const int row = y0 + ro + ky;
                const int xin = min(xcol + kx, W1 - 1);
                af = *(const bf16x8*)(a1 + (((size_t)b * H1 + row) * W1 + xin) * C1 + c0);
            }
            #pragma unroll
            for (int nf = 0; nf < 2; ++nf)
                acc[mi][nf] = __builtin_amdgcn_mfma_f32_16x16x32_bf16(af, bf[nf], acc[mi][nf], 0, 0, 0);
        }
    }

    #pragma unroll
    for (int mi = 0; mi < 4; ++mi) {
        const int m0 = w * 64 + mi * 16 + 4 * g;
        #pragma unroll
        for (int nf = 0; nf < 2; ++nf)
            #pragma unroll
            for (int r = 0; r < 4; ++r)
                sx2[m0 + r][nf * 16 + col] = f2bf(fmaxf(acc[mi][nf][r], 0.0f));
    }
    __syncthreads();

    // write rows y0, y0+1: 2 x 124 x 32 ch = 992 ushort8 chunks
    ushort* op = a2 + ((size_t)b * H2 + y0) * W2 * C2;
    for (int i = t; i < 992; i += 256) {
        int ro2 = i / 496, r = i % 496, xcol = r >> 2, c0 = (r & 3) * 8;
        *(bf16x8*)(op + ((size_t)ro2 * W2 + xcol) * C2 + c0) =
            *(const bf16x8*)(&sx2[ro2 * 128 + xcol][c0]);
    }
}

// ---------------- conv3: implicit GEMM MFMA + fused scores, 2 rows/block ----------------
// M=256, N=40 pad 48, K=288
__global__ __launch_bounds__(256) void k_conv3_mfma(const ushort* __restrict__ a2,
                                                    const ushort* __restrict__ bt3,
                                                    const float* __restrict__ b3,
                                                    const float* __restrict__ qkw,
                                                    float* __restrict__ x,
                                                    float* __restrict__ att) {
    __shared__ float sx[256][41];
    __shared__ float lq[160];
    const int b = blockIdx.y, y0 = blockIdx.x * 2;
    const int t = threadIdx.x, lane = t & 63, w = t >> 6;
    const int col = lane & 15, g = lane >> 4;
    const int ro = w >> 1, xbase = (w & 1) * 64;

    f32x4 acc[4][3];
    #pragma unroll
    for (int mi = 0; mi < 4; ++mi)
        #pragma unroll
        for (int nf = 0; nf < 3; ++nf) {
            const int ch = nf * 16 + col;
            float bv = (ch < 40) ? b3[ch] : 0.f;
            acc[mi][nf] = (f32x4){bv, bv, bv, bv};
        }

    #pragma unroll
    for (int ky = 0; ky < 3; ++ky) {
        #pragma unroll
        for (int kx = 0; kx < 3; ++kx) {
            const int ks = ky * 3 + kx;
            bf16x8 bf[3];
            #pragma unroll
            for (int nf = 0; nf < 3; ++nf)
                bf[nf] = *(const bf16x8*)(bt3 + (size_t)(nf * 16 + col) * 288 + ks * 32 + 8 * g);
            const ushort* arow = a2 + ((size_t)b * H2 + (y0 + ro + ky)) * W2 * C2;
            #pragma unroll
            for (int mi = 0; mi < 4; ++mi) {
                const int xcol = xbase + mi * 16 + col;
                const int xin = min(xcol + kx, W2 - 1);
                bf16x8 af = *(const bf16x8*)(arow + (size_t)xin * C2 + 8 * g);
                #pragma unroll
                for (int nf = 0; nf < 3; ++nf)
                    acc[mi][nf] = __builtin_amdgcn_mfma_f32_16x16x32_bf16(af, bf[nf], acc[mi][nf], 0, 0, 0);
            }
        }
    }

    for (int i = t; i < 160; i += 256) lq[i] = qkw[i];
    #pragma unroll
    for (int mi = 0; mi < 4; ++mi) {
        const int m0 = w * 64 + mi * 16 + 4 * g;
        #pragma unroll
        for (int nf = 0; nf < 3; ++nf) {
            const int ch = nf * 16 + col;
            if (ch < 40) {
                #pragma unroll
                for (int r = 0; r < 4; ++r)
                    sx[m0 + r][ch] = fmaxf(acc[mi][nf][r], 0.0f);
            }
        }
    }
    __syncthreads();

    // epilogue: 244 positions (2 rows x 122)
    if (t < 244) {
        const int ro2 = (t >= 122) ? 1 : 0;
        const int xcol = t - ro2 * 122;
        const int srow = ro2 * 128 + xcol;
        const int p = (y0 + ro2) * W3 + xcol;
        float* xp = x + (size_t)b * C3 * HW3 + p;
        float s0 = 0, s1 = 0, s2 = 0, s3 = 0;
        #pragma unroll
        for (int c = 0; c < 40; ++c) {
            float v = sx[srow][c];
            xp[(size_t)c * HW3] = v;
            s0 = fmaf(v, lq[c], s0);
            s1 = fmaf(v, lq[40 + c], s1);
            s2 = fmaf(v, lq[80 + c], s2);
            s3 = fmaf(v, lq[120 + c], s3);
        }
        float* ap = att + (size_t)b * 4 * HW3 + p;
        ap[0] = s0; ap[HW3] = s1; ap[2 * HW3] = s2; ap[3 * HW3] = s3;
    }
}

// ---------------- block reduction helpers ----------------
__device__ __forceinline__ float block_max(float v, float* sred) {
    #pragma unroll
    for (int off = 32; off >= 1; off >>= 1) v = fmaxf(v, __shfl_xor(v, off));
    if ((threadIdx.x & 63) == 0) sred[threadIdx.x >> 6] = v;
    __syncthreads();
    float r = fmaxf(fmaxf(sred[0], sred[1]), fmaxf(sred[2], sred[3]));
    __syncthreads();
    return r;
}
__device__ __forceinline__ float block_sum(float v, float* sred) {
    #pragma unroll
    for (int off = 32; off >= 1; off >>= 1) v += __shfl_xor(v, off);
    if ((threadIdx.x & 63) == 0) sred[threadIdx.x >> 6] = v;
    __syncthreads();
    float r = sred[0] + sred[1] + sred[2] + sred[3];
    __syncthreads();
    return r;
}

// ---------------- softmax (online max+sum single read pass), fuses pt_out ----------------
__global__ __launch_bounds__(256) void k_softmax(float* __restrict__ att,
                                                 float* __restrict__ pt_out) {
    __shared__ float sred[4];
    const int bq = blockIdx.x;
    float* row = att + (size_t)bq * HW3;
    const int t = threadIdx.x;

    float m_t = -1e30f, s_t = 0.f;
    for (int p = t; p < HW3; p += 256) {
        float v = row[p];
        if (v <= m_t) {
            s_t += __expf(v - m_t);
        } else {
            s_t = s_t * __expf(m_t - v) + 1.0f;
            m_t = v;
        }
    }
    float M = block_max(m_t, sred);
    s_t *= __expf(m_t - M);
    float S = block_sum(s_t, sred);
    const float inv = 1.0f / S;

    float sx = 0.f, sy = 0.f;
    for (int p = t; p < HW3; p += 256) {
        float wgt = __expf(row[p] - M) * inv;
        row[p] = wgt;
        int pr = p / W3, pc = p % W3;
        sx = fmaf(wgt, (float)pc * (1.0f / (W3 - 1)), sx);
        sy = fmaf(wgt, (float)pr * (1.0f / (H3 - 1)), sy);
    }
    sx = block_sum(sx, sred);
    sy = block_sum(sy, sred);
    if (t == 0) { pt_out[bq * 2] = sx; pt_out[bq * 2 + 1] = sy; }
}

// ---------------- s[b][q][c] = sum_p att[b,q,p] * x[b,c,p] ----------------
__global__ __launch_bounds__(256) void k_smat(const float* __restrict__ x,
                                              const float* __restrict__ att,
                                              float* __restrict__ smat) {
    __shared__ float sred[4];
    const int c = blockIdx.x, b = blockIdx.y;
    const float* xp = x + ((size_t)b * C3 + c) * HW3;
    const float* ap = att + (size_t)b * 4 * HW3;
    float a0 = 0, a1 = 0, a2 = 0, a3 = 0;
    for (int p = threadIdx.x; p < HW3; p += 256) {
        float v = xp[p];
        a0 = fmaf(v, ap[p], a0);
        a1 = fmaf(v, ap[HW3 + p], a1);
        a2 = fmaf(v, ap[2 * HW3 + p], a2);
        a3 = fmaf(v, ap[3 * HW3 + p], a3);
    }
    a0 = block_sum(a0, sred);
    a1 = block_sum(a1, sred);
    a2 = block_sum(a2, sred);
    a3 = block_sum(a3, sred);
    if (threadIdx.x == 0) {
        smat[((size_t)b * 4 + 0) * 40 + c] = a0;
        smat[((size_t)b * 4 + 1) * 40 + c] = a1;
        smat[((size_t)b * 4 + 2) * 40 + c] = a2;
        smat[((size_t)b * 4 + 3) * 40 + c] = a3;
    }
}

// ---------------- feat_out ----------------
__global__ void k_feat(const float* __restrict__ smat, const float* __restrict__ f_w,
                       float* __restrict__ feat) {
    const int b = blockIdx.x, t = threadIdx.x;
    if (t < 40) {
        int q = t / 10, d = t % 10;
        float s = 0.f;
        #pragma unroll
        for (int c = 0; c < 40; ++c)
            s = fmaf(f_w[(d * 4 + q) * 40 + c], smat[((size_t)b * 4 + q) * 40 + c], s);
        feat[b * 40 + t] = s;
    }
}

// ---------------- launch ----------------
extern "C" void kernel_launch(void* const* d_in, const int* in_sizes, int n_in,
                              void* d_out, int out_size, void* d_ws, size_t ws_size,
                              hipStream_t stream) {
    const float* img   = (const float*)d_in[0];
    const float* w1    = (const float*)d_in[1];
    const float* b1    = (const float*)d_in[2];
    const float* w2    = (const float*)d_in[3];
    const float* b2    = (const float*)d_in[4];
    const float* w3    = (const float*)d_in[5];
    const float* b3    = (const float*)d_in[6];
    const float* k_w   = (const float*)d_in[7];
    const float* f_w   = (const float*)d_in[8];
    const float* query = (const float*)d_in[9];

    char* ws = (char*)d_ws;
    ushort* imgN = (ushort*)(ws + IMGN_B);
    ushort* a1   = (ushort*)(ws + A1_B);
    ushort* a2   = (ushort*)(ws + A2_B);
    ushort* bt1  = (ushort*)(ws + BT1_B);
    ushort* bt2  = (ushort*)(ws + BT2_B);
    ushort* bt3  = (ushort*)(ws + BT3_B);
    float*  qkw  = (float*)(ws + QKW_B);
    float*  smat = (float*)(ws + SMAT_B);

    float* out  = (float*)d_out;
    float* x    = out;
    float* pt   = out + PT_OFF;
    float* feat = out + FEAT_OFF;
    float* att  = out + ATT_OFF;

    k_qkw<<<1, 256, 0, stream>>>(query, k_w, qkw);
    k_bt<<<80, 256, 0, stream>>>(w1, bt1, w2, bt2, w3, bt3);
    k_imgN<<<(BATCH * 16384) / 256, 256, 0, stream>>>(img, imgN);
    k_conv1_mfma<<<dim3(63, BATCH), 256, 0, stream>>>(imgN, bt1, b1, a1);
    k_conv2_mfma<<<dim3(62, BATCH), 256, 0, stream>>>(a1, bt2, b2, a2);
    k_conv3_mfma<<<dim3(61, BATCH), 256, 0, stream>>>(a2, bt3, b3, qkw, x, att);
    k_softmax<<<BATCH * 4, 256, 0, stream>>>(att, pt);
    k_smat<<<dim3(40, BATCH), 256, 0, stream>>>(x, att, smat);
    k_feat<<<BATCH, 64, 0, stream>>>(smat, f_w, feat);
}